// Round 4
// baseline (408.651 us; speedup 1.0000x reference)
//
#include <hip/hip_runtime.h>

#define D_MODEL 2048
#define B_SZ 4
#define T_SZ 2048
#define N_SZ 512

typedef __bf16 bf16x8 __attribute__((ext_vector_type(8)));
typedef float f32x4 __attribute__((ext_vector_type(4)));
typedef ushort u16x8 __attribute__((ext_vector_type(8)));

// fp32 -> bf16 round-to-nearest-even
__device__ __forceinline__ ushort f2bf(float f) {
  unsigned u = __float_as_uint(f);
  unsigned r = (u + 0x7fffu + ((u >> 16) & 1u)) >> 16;
  return (ushort)r;
}
__device__ __forceinline__ float bflo(unsigned w) { return __uint_as_float(w << 16); }
__device__ __forceinline__ float bfhi(unsigned w) { return __uint_as_float(w & 0xffff0000u); }

__device__ __forceinline__ void async_ld16(const ushort* g, ushort* l) {
  __builtin_amdgcn_global_load_lds(
      (const __attribute__((address_space(1))) void*)g,
      (__attribute__((address_space(3))) void*)l, 16, 0, 0);
}

// fp32 -> bf16 elementwise, 8 elems/thread. n must be a multiple of 2048.
__global__ __launch_bounds__(256) void conv_bf16(const float* __restrict__ src,
                                                 ushort* __restrict__ dst) {
  const long i = ((long)blockIdx.x * 256 + threadIdx.x) * 8;
  float4 a = *(const float4*)(src + i);
  float4 b = *(const float4*)(src + i + 4);
  u16x8 o;
  o[0] = f2bf(a.x); o[1] = f2bf(a.y); o[2] = f2bf(a.z); o[3] = f2bf(a.w);
  o[4] = f2bf(b.x); o[5] = f2bf(b.y); o[6] = f2bf(b.z); o[7] = f2bf(b.w);
  *(u16x8*)(dst + i) = o;
}

// h_stack (B,N,D) fp32 -> hsT (B,D,N) bf16
__global__ __launch_bounds__(256) void transpose_conv(const float* __restrict__ src,
                                                      ushort* __restrict__ dst) {
  __shared__ ushort tile[32][33];
  const int b = blockIdx.z;
  const int n0 = blockIdx.x * 32, d0 = blockIdx.y * 32;
  const int tx = threadIdx.x, ty = threadIdx.y;  // (32,8)
  const float* s = src + (long)b * N_SZ * D_MODEL;
  ushort* d = dst + (long)b * D_MODEL * N_SZ;
#pragma unroll
  for (int r = 0; r < 4; r++)
    tile[ty + r * 8][tx] = f2bf(s[(long)(n0 + ty + r * 8) * D_MODEL + d0 + tx]);
  __syncthreads();
#pragma unroll
  for (int r = 0; r < 4; r++)
    d[(long)(d0 + ty + r * 8) * N_SZ + n0 + tx] = tile[tx][ty + r * 8];
}

// C[M,N] = A[M,K] * Bt[N,K]^T   (row-major, K contiguous, bf16 in, scale on out)
// MASKMODE 0: none. 1: skip tile if col0 > (t_max>>2). 2: truncate K to gates' range.
// OUT_BF16: u (internal ws) is bf16; scores / h_retrieved are fp32.
template <int MASKMODE, bool OUT_BF16>
__global__ __launch_bounds__(256) void gemm_bt(const ushort* __restrict__ A,
                                               const ushort* __restrict__ Bt,
                                               void* __restrict__ Cv, int M, int N, int K,
                                               long sA, long sB, long sC, float scale) {
  __shared__ __align__(16) ushort sa[128 * 32];
  __shared__ __align__(16) ushort sb[128 * 32];
  const int bz = blockIdx.z;
  const int row0 = blockIdx.y * 128;
  const int col0 = blockIdx.x * 128;
  if (MASKMODE == 1 && col0 > ((row0 + 127) >> 2)) return;
  int Kend = K;
  if (MASKMODE == 2) {
    int kl = ((row0 + 127) >> 2) + 1;
    Kend = min(K, (kl + 31) & ~31);
  }
  const ushort* Ab = A + (long)bz * sA;
  const ushort* Bb = Bt + (long)bz * sB;

  const int tid = threadIdx.x;
  const int w = tid >> 6, lane = tid & 63;
  const int wr = w >> 1, wc = w & 1;
  const int quad = lane >> 4, l16 = lane & 15;

  f32x4 acc[4][4];
#pragma unroll
  for (int i = 0; i < 4; i++)
#pragma unroll
    for (int j = 0; j < 4; j++) acc[i][j] = (f32x4){0.f, 0.f, 0.f, 0.f};

  // async staging: 128x32 bf16 tile = 8KB, 16 chunks of 1KB; wave w owns chunks
  // 2w,2w+1 of A and B. lane l -> LDS base + l*16B = row ch*16+l/4, col (l&3)*8.
  // (semantics validated: r2 async and r3 explicit staging gave identical bits)
  const int ch = w * 2;
  const int srow = ch * 16 + (lane >> 2);
  const int scol = (lane & 3) * 8;
  ushort* ldsA0 = sa + ch * 512;
  ushort* ldsA1 = sa + ch * 512 + 512;
  ushort* ldsB0 = sb + ch * 512;
  ushort* ldsB1 = sb + ch * 512 + 512;
  const ushort* gA0 = Ab + (long)(row0 + srow) * K + scol;
  const ushort* gA1 = Ab + (long)(row0 + srow + 16) * K + scol;
  const ushort* gB0 = Bb + (long)(col0 + srow) * K + scol;
  const ushort* gB1 = Bb + (long)(col0 + srow + 16) * K + scol;

  for (int k0 = 0; k0 < Kend; k0 += 32) {
    async_ld16(gA0 + k0, ldsA0);
    async_ld16(gA1 + k0, ldsA1);
    async_ld16(gB0 + k0, ldsB0);
    async_ld16(gB1 + k0, ldsB1);
    __syncthreads();  // drains global_load_lds (vmcnt) + barrier
    bf16x8 af[4], bfr[4];
#pragma unroll
    for (int i = 0; i < 4; i++) {
      af[i] = *(const bf16x8*)(sa + (wr * 64 + i * 16 + l16) * 32 + quad * 8);
      bfr[i] = *(const bf16x8*)(sb + (wc * 64 + i * 16 + l16) * 32 + quad * 8);
    }
#pragma unroll
    for (int i = 0; i < 4; i++)
#pragma unroll
      for (int j = 0; j < 4; j++)
        acc[i][j] = __builtin_amdgcn_mfma_f32_16x16x32_bf16(af[i], bfr[j], acc[i][j], 0, 0, 0);
    __syncthreads();  // protect LDS before next iteration's staging
  }

#pragma unroll
  for (int i = 0; i < 4; i++) {
    const int rb = row0 + wr * 64 + i * 16 + quad * 4;
#pragma unroll
    for (int j = 0; j < 4; j++) {
      const int c = col0 + wc * 64 + j * 16 + l16;
#pragma unroll
      for (int r = 0; r < 4; r++) {
        float v = acc[i][j][r] * scale;
        long off = (long)bz * sC + (long)(rb + r) * N + c;
        if (OUT_BF16)
          ((ushort*)Cv)[off] = f2bf(v);
        else
          ((float*)Cv)[off] = v;
      }
    }
  }
}

// one block per (b,t): current-score dot (u bf16 · m_current fp32), masked softmax over 513.
// outputs fp32 (harness buffer dtype = reference output dtype = float32); gates ws stays bf16.
__global__ __launch_bounds__(256) void softmax_gate(const ushort* __restrict__ u_bf,
                                                    const float* __restrict__ m_cur,
                                                    const float* __restrict__ scores,
                                                    float* __restrict__ out_gc,
                                                    float* __restrict__ out_attn,
                                                    ushort* __restrict__ gates_bf) {
  __shared__ float red[256];
  const int bt = blockIdx.x;
  const int t = bt & (T_SZ - 1);
  const int tid = threadIdx.x;
  const ushort* urow = u_bf + (long)bt * D_MODEL;
  const float* mrow = m_cur + (long)bt * D_MODEL;
  uint4 uv = *(const uint4*)(urow + tid * 8);
  float4 m0 = *(const float4*)(mrow + tid * 8);
  float4 m1 = *(const float4*)(mrow + tid * 8 + 4);
  float part = bflo(uv.x) * m0.x + bfhi(uv.x) * m0.y + bflo(uv.y) * m0.z + bfhi(uv.y) * m0.w +
               bflo(uv.z) * m1.x + bfhi(uv.z) * m1.y + bflo(uv.w) * m1.z + bfhi(uv.w) * m1.w;
  red[tid] = part;
  __syncthreads();
  for (int s = 128; s > 0; s >>= 1) {
    if (tid < s) red[tid] += red[tid + s];
    __syncthreads();
  }
  const float curs = red[0] * 0.022097086912079608f;  // 1/sqrt(2048)
  __syncthreads();

  const int nmax = t >> 2;  // mask: n <= t*N//T = t>>2 (inclusive)
  const float* srow = scores + (long)bt * N_SZ;
  float lmax = curs;
  for (int n = tid; n <= nmax; n += 256) lmax = fmaxf(lmax, srow[n]);
  red[tid] = lmax;
  __syncthreads();
  for (int s = 128; s > 0; s >>= 1) {
    if (tid < s) red[tid] = fmaxf(red[tid], red[tid + s]);
    __syncthreads();
  }
  const float M = red[0];
  __syncthreads();
  float lsum = (tid == 0) ? __expf(curs - M) : 0.f;
  for (int n = tid; n <= nmax; n += 256) lsum += __expf(srow[n] - M);
  red[tid] = lsum;
  __syncthreads();
  for (int s = 128; s > 0; s >>= 1) {
    if (tid < s) red[tid] += red[tid + s];
    __syncthreads();
  }
  const float inv = 1.f / red[0];

  float* arow = out_attn + (long)bt * (N_SZ + 1);
  ushort* grow = gates_bf + (long)bt * N_SZ;
  for (int n = tid; n < N_SZ; n += 256) {
    float wgt = (n <= nmax) ? __expf(srow[n] - M) * inv : 0.f;
    arow[n] = wgt;
    grow[n] = f2bf(wgt);
  }
  if (tid == 0) {
    float g = __expf(curs - M) * inv;
    arow[N_SZ] = g;
    out_gc[bt] = g;
  }
}

extern "C" void kernel_launch(void* const* d_in, const int* in_sizes, int n_in,
                              void* d_out, int out_size, void* d_ws, size_t ws_size,
                              hipStream_t stream) {
  const float* x = (const float*)d_in[0];        // (B,T,D) fp32
  const float* h_stack = (const float*)d_in[1];  // (B,N,D) fp32
  const float* m_stack = (const float*)d_in[2];  // (B,N,D) fp32
  const float* m_cur = (const float*)d_in[3];    // (B,T,D) fp32
  const float* W = (const float*)d_in[5];        // (D,D) fp32  (d_in[4] = mask, recomputed)

  float* out = (float*)d_out;  // fp32 = reference output dtype
  float* out_h = out;                                  // (B,T,D)
  float* out_gc = out + (long)B_SZ * T_SZ * D_MODEL;   // (B,T,1)
  float* out_attn = out_gc + B_SZ * T_SZ;              // (B,T,N+1)

  // workspace layout (112 MB total)
  char* ws = (char*)d_ws;
  ushort* x_bf = (ushort*)ws;               // B*T*D   = 16,777,216
  ushort* u_bf = x_bf + 16777216;           // B*T*D
  ushort* W_bf = u_bf + 16777216;           // D*D     =  4,194,304
  ushort* ms_bf = W_bf + 4194304;           // B*N*D
  ushort* gates = ms_bf + 4194304;          // B*T*N   =  4,194,304
  ushort* hsT = gates + 4194304;            // B*D*N
  float* scores = (float*)(hsT + 4194304);  // B*T*N fp32

  conv_bf16<<<16777216 / 2048, 256, 0, stream>>>(x, x_bf);
  conv_bf16<<<4194304 / 2048, 256, 0, stream>>>(W, W_bf);
  conv_bf16<<<4194304 / 2048, 256, 0, stream>>>(m_stack, ms_bf);
  transpose_conv<<<dim3(N_SZ / 32, D_MODEL / 32, B_SZ), dim3(32, 8), 0, stream>>>(h_stack, hsT);

  // u = x @ W^T  (M=8192, N=2048, K=2048), out bf16 (internal)
  gemm_bt<0, true><<<dim3(D_MODEL / 128, (B_SZ * T_SZ) / 128, 1), 256, 0, stream>>>(
      x_bf, W_bf, u_bf, B_SZ * T_SZ, D_MODEL, D_MODEL, 0, 0, 0, 1.0f);

  // scores = u @ m_stack^T * scale  per batch (M=2048, N=512, K=2048), fp32 out, masked tiles skipped
  gemm_bt<1, false><<<dim3(N_SZ / 128, T_SZ / 128, B_SZ), 256, 0, stream>>>(
      u_bf, ms_bf, scores, T_SZ, N_SZ, D_MODEL, (long)T_SZ * D_MODEL, (long)N_SZ * D_MODEL,
      (long)T_SZ * N_SZ, 0.022097086912079608f);

  softmax_gate<<<B_SZ * T_SZ, 256, 0, stream>>>(u_bf, m_cur, scores, out_gc, out_attn, gates);

  // h = gates @ hsT^T  per batch (M=2048, N=2048, K=512 truncated), fp32 out
  gemm_bt<2, false><<<dim3(D_MODEL / 128, T_SZ / 128, B_SZ), 256, 0, stream>>>(
      gates, hsT, out_h, T_SZ, D_MODEL, N_SZ, (long)T_SZ * N_SZ, (long)D_MODEL * N_SZ,
      (long)T_SZ * D_MODEL, 1.0f);
}

// Round 5
// 394.757 us; speedup vs baseline: 1.0352x; 1.0352x over previous
//
#include <hip/hip_runtime.h>

#define D_MODEL 2048
#define B_SZ 4
#define T_SZ 2048
#define N_SZ 512

typedef __bf16 bf16x8 __attribute__((ext_vector_type(8)));
typedef float f32x4 __attribute__((ext_vector_type(4)));
typedef ushort u16x8 __attribute__((ext_vector_type(8)));

// fp32 -> bf16 round-to-nearest-even
__device__ __forceinline__ ushort f2bf(float f) {
  unsigned u = __float_as_uint(f);
  unsigned r = (u + 0x7fffu + ((u >> 16) & 1u)) >> 16;
  return (ushort)r;
}
__device__ __forceinline__ float bflo(unsigned w) { return __uint_as_float(w << 16); }
__device__ __forceinline__ float bfhi(unsigned w) { return __uint_as_float(w & 0xffff0000u); }

__device__ __forceinline__ void async_ld16(const ushort* g, ushort* l) {
  __builtin_amdgcn_global_load_lds(
      (const __attribute__((address_space(1))) void*)g,
      (__attribute__((address_space(3))) void*)l, 16, 0, 0);
}

// single fused fp32->bf16 conversion for x (8192 blk), W (2048 blk), m_stack (2048 blk)
__global__ __launch_bounds__(256) void conv_all(const float* __restrict__ x,
                                                const float* __restrict__ W,
                                                const float* __restrict__ ms,
                                                ushort* __restrict__ x_bf,
                                                ushort* __restrict__ W_bf,
                                                ushort* __restrict__ ms_bf) {
  const int bid = blockIdx.x;
  const float* src;
  ushort* dst;
  long blk;
  if (bid < 8192) { src = x; dst = x_bf; blk = bid; }
  else if (bid < 10240) { src = W; dst = W_bf; blk = bid - 8192; }
  else { src = ms; dst = ms_bf; blk = bid - 10240; }
  const long i = (blk * 256 + threadIdx.x) * 8;
  float4 a = *(const float4*)(src + i);
  float4 b = *(const float4*)(src + i + 4);
  u16x8 o;
  o[0] = f2bf(a.x); o[1] = f2bf(a.y); o[2] = f2bf(a.z); o[3] = f2bf(a.w);
  o[4] = f2bf(b.x); o[5] = f2bf(b.y); o[6] = f2bf(b.z); o[7] = f2bf(b.w);
  *(u16x8*)(dst + i) = o;
}

// h_stack (B,N,D) fp32 -> hsT (B,D,N) bf16
__global__ __launch_bounds__(256) void transpose_conv(const float* __restrict__ src,
                                                      ushort* __restrict__ dst) {
  __shared__ ushort tile[32][33];
  const int b = blockIdx.z;
  const int n0 = blockIdx.x * 32, d0 = blockIdx.y * 32;
  const int tx = threadIdx.x, ty = threadIdx.y;  // (32,8)
  const float* s = src + (long)b * N_SZ * D_MODEL;
  ushort* d = dst + (long)b * D_MODEL * N_SZ;
#pragma unroll
  for (int r = 0; r < 4; r++)
    tile[ty + r * 8][tx] = f2bf(s[(long)(n0 + ty + r * 8) * D_MODEL + d0 + tx]);
  __syncthreads();
#pragma unroll
  for (int r = 0; r < 4; r++)
    d[(long)(d0 + ty + r * 8) * N_SZ + n0 + tx] = tile[tx][ty + r * 8];
}

// C[M,N] = A[M,K] * Bt[N,K]^T  (row-major, K contiguous, bf16 in, scale on out)
// TM in {128,64}: row-tile. col-tile fixed 128. 4 waves: wr=w>>1, wc=w&1,
// wave-tile (TM/2)x64. MASKMODE 0: none. 1: skip tile if col0 > (t_max>>2).
// 2: truncate K to gates' nonzero range.
template <int TM, int MASKMODE, bool OUT_BF16>
__global__ __launch_bounds__(256) void gemm_bt(const ushort* __restrict__ A,
                                               const ushort* __restrict__ Bt,
                                               void* __restrict__ Cv, int N, int K,
                                               long sA, long sB, long sC, float scale) {
  constexpr int NA = TM / 16;   // A-tile 1KB chunks
  constexpr int NCH = NA + 8;   // total chunks (B-tile has 8)
  constexpr int NC = NCH / 4;   // chunks per wave
  constexpr int NI = TM / 32;   // i-blocks per wave
  __shared__ __align__(16) ushort sa[TM * 32];
  __shared__ __align__(16) ushort sb[128 * 32];
  const int bz = blockIdx.z;
  const int row0 = blockIdx.y * TM;
  const int col0 = blockIdx.x * 128;
  if (MASKMODE == 1 && col0 > ((row0 + TM - 1) >> 2)) return;
  int Kend = K;
  if (MASKMODE == 2) {
    int kl = ((row0 + TM - 1) >> 2) + 1;
    Kend = min(K, (kl + 31) & ~31);
  }
  const ushort* Ab = A + (long)bz * sA;
  const ushort* Bb = Bt + (long)bz * sB;

  const int tid = threadIdx.x;
  const int w = tid >> 6, lane = tid & 63;
  const int wr = w >> 1, wc = w & 1;
  const int quad = lane >> 4, l16 = lane & 15;

  f32x4 acc[NI][4];
#pragma unroll
  for (int i = 0; i < NI; i++)
#pragma unroll
    for (int j = 0; j < 4; j++) acc[i][j] = (f32x4){0.f, 0.f, 0.f, 0.f};

  // staging: chunk = 16 rows x 32 k (1 KB); lane l -> LDS base + l*16B
  // = row l/4, k-col (l&3)*8 within chunk. wave w owns chunks w*NC..w*NC+NC-1
  // of the concatenated [A chunks (NA), B chunks (8)] list.
  const int lrow = lane >> 2;
  const int lcol = (lane & 3) * 8;
  const ushort* gsrc[NC];
  ushort* ldst[NC];
#pragma unroll
  for (int t = 0; t < NC; t++) {
    const int c = w * NC + t;
    if (c < NA) {
      ldst[t] = sa + c * 512;
      gsrc[t] = Ab + (long)(row0 + c * 16 + lrow) * K + lcol;
    } else {
      ldst[t] = sb + (c - NA) * 512;
      gsrc[t] = Bb + (long)(col0 + (c - NA) * 16 + lrow) * K + lcol;
    }
  }

  for (int k0 = 0; k0 < Kend; k0 += 32) {
#pragma unroll
    for (int t = 0; t < NC; t++) async_ld16(gsrc[t] + k0, ldst[t]);
    __syncthreads();  // drains global_load_lds (vmcnt) + barrier
    bf16x8 af[NI], bfr[4];
#pragma unroll
    for (int i = 0; i < NI; i++)
      af[i] = *(const bf16x8*)(sa + (wr * (TM / 2) + i * 16 + l16) * 32 + quad * 8);
#pragma unroll
    for (int j = 0; j < 4; j++)
      bfr[j] = *(const bf16x8*)(sb + (wc * 64 + j * 16 + l16) * 32 + quad * 8);
#pragma unroll
    for (int i = 0; i < NI; i++)
#pragma unroll
      for (int j = 0; j < 4; j++)
        acc[i][j] = __builtin_amdgcn_mfma_f32_16x16x32_bf16(af[i], bfr[j], acc[i][j], 0, 0, 0);
    __syncthreads();  // all reads done before next iteration's staging
  }

#pragma unroll
  for (int i = 0; i < NI; i++) {
    const int rb = row0 + wr * (TM / 2) + i * 16 + quad * 4;
#pragma unroll
    for (int j = 0; j < 4; j++) {
      const int c = col0 + wc * 64 + j * 16 + l16;
#pragma unroll
      for (int r = 0; r < 4; r++) {
        float v = acc[i][j][r] * scale;
        long off = (long)bz * sC + (long)(rb + r) * N + c;
        if (OUT_BF16)
          ((ushort*)Cv)[off] = f2bf(v);
        else
          ((float*)Cv)[off] = v;
      }
    }
  }
}

// one WAVE per (b,t) row: current-score dot + masked softmax over 513.
// no __syncthreads — pure shuffle butterflies. 4 rows per block.
__global__ __launch_bounds__(256) void softmax_gate(const ushort* __restrict__ u_bf,
                                                    const float* __restrict__ m_cur,
                                                    const float* __restrict__ scores,
                                                    float* __restrict__ out_gc,
                                                    float* __restrict__ out_attn,
                                                    ushort* __restrict__ gates_bf) {
  const int wv = threadIdx.x >> 6, lane = threadIdx.x & 63;
  const int bt = blockIdx.x * 4 + wv;
  const int t = bt & (T_SZ - 1);
  const ushort* urow = u_bf + (long)bt * D_MODEL;
  const float* mrow = m_cur + (long)bt * D_MODEL;

  float part = 0.f;
#pragma unroll
  for (int c = 0; c < 4; c++) {
    uint4 uv = *(const uint4*)(urow + c * 512 + lane * 8);
    float4 m0 = *(const float4*)(mrow + c * 512 + lane * 8);
    float4 m1 = *(const float4*)(mrow + c * 512 + lane * 8 + 4);
    part += bflo(uv.x) * m0.x + bfhi(uv.x) * m0.y + bflo(uv.y) * m0.z + bfhi(uv.y) * m0.w +
            bflo(uv.z) * m1.x + bfhi(uv.z) * m1.y + bflo(uv.w) * m1.z + bfhi(uv.w) * m1.w;
  }
#pragma unroll
  for (int m = 32; m; m >>= 1) part += __shfl_xor(part, m, 64);
  const float curs = part * 0.022097086912079608f;  // 1/sqrt(2048)

  const int nmax = t >> 2;  // mask: n <= t*N//T = t>>2 (inclusive)
  const float* srow = scores + (long)bt * N_SZ;
  float sc[8];
  float lmax = curs;
#pragma unroll
  for (int k = 0; k < 8; k++) {
    const int n = k * 64 + lane;
    sc[k] = srow[n];  // masked region holds valid (poison/stale) floats, never selected
    if (n <= nmax) lmax = fmaxf(lmax, sc[k]);
  }
#pragma unroll
  for (int m = 32; m; m >>= 1) lmax = fmaxf(lmax, __shfl_xor(lmax, m, 64));

  float lsum = (lane == 0) ? __expf(curs - lmax) : 0.f;
#pragma unroll
  for (int k = 0; k < 8; k++) {
    const int n = k * 64 + lane;
    sc[k] = (n <= nmax) ? __expf(sc[k] - lmax) : 0.f;
    lsum += sc[k];
  }
#pragma unroll
  for (int m = 32; m; m >>= 1) lsum += __shfl_xor(lsum, m, 64);
  const float inv = 1.f / lsum;

  float* arow = out_attn + (long)bt * (N_SZ + 1);
  ushort* grow = gates_bf + (long)bt * N_SZ;
#pragma unroll
  for (int k = 0; k < 8; k++) {
    const int n = k * 64 + lane;
    const float wgt = sc[k] * inv;
    arow[n] = wgt;
    grow[n] = f2bf(wgt);
  }
  if (lane == 0) {
    const float g = __expf(curs - lmax) * inv;
    arow[N_SZ] = g;
    out_gc[bt] = g;
  }
}

extern "C" void kernel_launch(void* const* d_in, const int* in_sizes, int n_in,
                              void* d_out, int out_size, void* d_ws, size_t ws_size,
                              hipStream_t stream) {
  const float* x = (const float*)d_in[0];        // (B,T,D) fp32
  const float* h_stack = (const float*)d_in[1];  // (B,N,D) fp32
  const float* m_stack = (const float*)d_in[2];  // (B,N,D) fp32
  const float* m_cur = (const float*)d_in[3];    // (B,T,D) fp32
  const float* W = (const float*)d_in[5];        // (D,D) fp32  (d_in[4] = mask, recomputed)

  float* out = (float*)d_out;  // fp32 = reference output dtype
  float* out_h = out;                                 // (B,T,D)
  float* out_gc = out + (long)B_SZ * T_SZ * D_MODEL;  // (B,T,1)
  float* out_attn = out_gc + B_SZ * T_SZ;             // (B,T,N+1)

  // workspace layout (112 MB total)
  char* ws = (char*)d_ws;
  ushort* x_bf = (ushort*)ws;               // B*T*D   = 16,777,216
  ushort* u_bf = x_bf + 16777216;           // B*T*D
  ushort* W_bf = u_bf + 16777216;           // D*D     =  4,194,304
  ushort* ms_bf = W_bf + 4194304;           // B*N*D
  ushort* gates = ms_bf + 4194304;          // B*T*N   =  4,194,304
  ushort* hsT = gates + 4194304;            // B*D*N
  float* scores = (float*)(hsT + 4194304);  // B*T*N fp32

  conv_all<<<12288, 256, 0, stream>>>(x, W, m_stack, x_bf, W_bf, ms_bf);
  transpose_conv<<<dim3(N_SZ / 32, D_MODEL / 32, B_SZ), dim3(32, 8), 0, stream>>>(h_stack, hsT);

  // u = x @ W^T  (M=8192, N=2048, K=2048), out bf16 (internal)
  gemm_bt<128, 0, true><<<dim3(D_MODEL / 128, (B_SZ * T_SZ) / 128, 1), 256, 0, stream>>>(
      x_bf, W_bf, u_bf, D_MODEL, D_MODEL, 0, 0, 0, 1.0f);

  // scores = u @ m_stack^T * scale  per batch (M=2048, N=512, K=2048), fp32 out.
  // TM=64 -> 320 active blocks (vs 160 at TM=128): better CU coverage.
  gemm_bt<64, 1, false><<<dim3(N_SZ / 128, T_SZ / 64, B_SZ), 256, 0, stream>>>(
      u_bf, ms_bf, scores, N_SZ, D_MODEL, (long)T_SZ * D_MODEL, (long)N_SZ * D_MODEL,
      (long)T_SZ * N_SZ, 0.022097086912079608f);

  softmax_gate<<<(B_SZ * T_SZ) / 4, 256, 0, stream>>>(u_bf, m_cur, scores, out_gc, out_attn,
                                                      gates);

  // h = gates @ hsT^T  per batch (M=2048, N=2048, K=512 truncated), fp32 out
  gemm_bt<128, 2, false><<<dim3(D_MODEL / 128, T_SZ / 128, B_SZ), 256, 0, stream>>>(
      gates, hsT, out_h, D_MODEL, N_SZ, (long)T_SZ * N_SZ, (long)D_MODEL * N_SZ,
      (long)T_SZ * D_MODEL, 1.0f);
}